// Round 2
// baseline (778.180 us; speedup 1.0000x reference)
//
#include <hip/hip_runtime.h>
#include <stdint.h>

// Problem dims (fixed): x [M,K] fp32, W [K,N] fp32 ternary, b [N] fp32.
// out = concat( sign(z) [M,N], z [M,N] ), z = x@W + b, all fp32.
#define MDIM 8192
#define NDIM 4096
#define KDIM 4096

// 8-phase GEMM geometry (256x256 tile, BK=64, 8 waves 2Mx4N)
#define BM 256
#define BN 256
#define BK 64
#define NT (KDIM / BK)  // 64 K-tiles

#define CVT_W_BLOCKS 4096   // (N/64)*(K/64)

typedef __bf16 bf16x8 __attribute__((ext_vector_type(8)));
typedef float f32x4 __attribute__((ext_vector_type(4)));

#define GPTR(p) ((const __attribute__((address_space(1))) void*)(p))
#define LPTR(p) ((__attribute__((address_space(3))) void*)(p))

// Raw barrier with compiler memory fence.
#define BAR() asm volatile("s_barrier" ::: "memory")

__device__ __forceinline__ uint32_t f2bf(float f) {
  union { float f; uint32_t u; } c; c.f = f;
  uint32_t u = c.u;
  u += 0x7fffu + ((u >> 16) & 1u);   // RTNE
  return u >> 16;
}

// packed f32x2 -> bf16x2 (RTNE), low half = bf16(lo). No builtin on gfx950.
__device__ __forceinline__ uint32_t cvtpk(float lo, float hi) {
  uint32_t r;
  asm("v_cvt_pk_bf16_f32 %0, %1, %2" : "=v"(r) : "v"(lo), "v"(hi));
  return r;
}

// ---------------- W conversion kernel (W-part of verified cvt_fused) --------
// W [K,N] -> Wt [N,K] bf16, 64x64 LDS transpose tile (ld=37).
__global__ __launch_bounds__(256) void cvt_w(const float* __restrict__ W,
                                             unsigned short* __restrict__ Wt) {
  __shared__ uint32_t T[64][37];
  const int wb = blockIdx.x;
  const int t = threadIdx.x;
  const int n0 = (wb & 63) * 64;
  const int k0 = (wb >> 6) * 64;
  const int nl = t & 63;
  const int kpb = t >> 6;  // 0..3
#pragma unroll
  for (int i = 0; i < 8; ++i) {
    int kp = kpb + 4 * i;  // pair of k rows
    int k = 2 * kp;
    float v0 = W[(size_t)(k0 + k) * NDIM + n0 + nl];
    float v1 = W[(size_t)(k0 + k + 1) * NDIM + n0 + nl];
    T[nl][kp] = f2bf(v0) | (f2bf(v1) << 16);
  }
  __syncthreads();
  const int ch = t & 7;   // 16B chunk (8 k)
  const int nb = t >> 3;  // 0..31
#pragma unroll
  for (int h = 0; h < 2; ++h) {
    int n = nb + 32 * h;
    uint4 v;
    v.x = T[n][ch * 4 + 0];
    v.y = T[n][ch * 4 + 1];
    v.z = T[n][ch * 4 + 2];
    v.w = T[n][ch * 4 + 3];
    *(uint4*)&Wt[(size_t)(n0 + n) * KDIM + k0 + ch * 8] = v;
  }
}

// ---------------- 8-phase 256x256 GEMM, A reg-staged from fp32 x ------------
// LDS layout per operand tile: [256 rows][64 K] bf16; chunk c of row r stored
// at chunk position c ^ (r&7) (zero-conflict ds_read_b128, verified).
// B: global_load_lds with pre-swizzled global source (rule 21, verified).
// A: reg-staged from fp32 x: issue 8 global_load_dwordx4 at P0/P1, then at P3
//    (after vmcnt) v_cvt_pk_bf16_f32 + 4x ds_write_b128 using the SAME
//    lane->(row,chunk) shape as the verified read pattern (0 conflicts).
//
// Per tile T (steady):
//  P0: ds_reads A-frags 0-3 + B-frags 0-1 | issue A(T+1) reads c=0,1
//  P1: ds_reads B-frags 2-3               | issue A(T+1) reads c=2,3
//  P2: ds_reads A-frags 4-7               | gload_lds B(T+2) half0
//  P3: gload_lds B(T+2) half1 | vmcnt(4)  -> completes A(T+1) reads AND
//      publishes B(T+1), keeps B(T+2)(4) in flight | cvt+ds_write A(T+1)
//      | BAR | mfma | lgkmcnt(0) | BAR  (publishes A(T+1))
// Buffer liveness: nxtA last READ at tile T-1 P2 (2+ barriers before writes);
// stageB (=curB buffer) last read at P1, staged at P2/P3 of same tile.

__device__ __forceinline__ void stage2(unsigned short* dst,
                                       const unsigned short* G, int half,
                                       int tile, int wave) {
#pragma unroll
  for (int i = 0; i < 2; ++i) {
    const int rb = half * 128 + i * 64;  // 64 rows per instruction (512 thr)
    __builtin_amdgcn_global_load_lds(
        GPTR(G + (size_t)rb * KDIM + (size_t)tile * 64),
        LPTR(dst + (rb + wave * 8) * BK), 16, 0, 0);
  }
}

// Issue 2 of the 4 A-chunk reads (fp32, 2 float4 each).
template <int C0>
__device__ __forceinline__ void issueA2(const float* const (&aptr)[4], int kf,
                                        float4 (&areg)[4][2]) {
#pragma unroll
  for (int c = C0; c < C0 + 2; ++c) {
    areg[c][0] = *(const float4*)(aptr[c] + kf);
    areg[c][1] = *(const float4*)(aptr[c] + kf + 4);
  }
}

// Convert + swizzled LDS write of the staged A tile.
__device__ __forceinline__ void writeA(unsigned short* nxtA,
                                       const int (&alds)[4],
                                       const float4 (&areg)[4][2]) {
#pragma unroll
  for (int c = 0; c < 4; ++c) {
    uint4 v;
    v.x = cvtpk(areg[c][0].x, areg[c][0].y);
    v.y = cvtpk(areg[c][0].z, areg[c][0].w);
    v.z = cvtpk(areg[c][1].x, areg[c][1].y);
    v.w = cvtpk(areg[c][1].z, areg[c][1].w);
    *(uint4*)(nxtA + alds[c]) = v;
  }
}

template <int IB>
__device__ __forceinline__ void load_a4(const unsigned short* buf, int wm,
                                        int rA, int k0off, int k1off,
                                        bf16x8 (&a)[4][2]) {
#pragma unroll
  for (int i = 0; i < 4; ++i) {
    const unsigned short* p = buf + (size_t)(wm * 128 + (IB + i) * 16 + rA) * BK;
    a[i][0] = *(const bf16x8*)(p + k0off);
    a[i][1] = *(const bf16x8*)(p + k1off);
  }
}

template <int JB>
__device__ __forceinline__ void load_b2(const unsigned short* buf, int wn,
                                        int rA, int k0off, int k1off,
                                        bf16x8 (&b)[4][2]) {
#pragma unroll
  for (int j = 0; j < 2; ++j) {
    const unsigned short* p = buf + (size_t)(wn * 64 + (JB + j) * 16 + rA) * BK;
    b[JB + j][0] = *(const bf16x8*)(p + k0off);
    b[JB + j][1] = *(const bf16x8*)(p + k1off);
  }
}

// OPERAND SWAP (verified): acc = mfma(b, a, acc) -> lane l: m = l&15,
// n = (l>>4)*4 + reg  => float4 epilogue stores along n.
template <int IB, int JB>
__device__ __forceinline__ void mfma16(const bf16x8 (&a)[4][2],
                                       const bf16x8 (&b)[4][2],
                                       f32x4 (&acc)[8][4]) {
  __builtin_amdgcn_s_setprio(1);
#pragma unroll
  for (int i = 0; i < 4; ++i)
#pragma unroll
    for (int j = 0; j < 2; ++j)
#pragma unroll
      for (int kk = 0; kk < 2; ++kk)
        acc[IB + i][JB + j] = __builtin_amdgcn_mfma_f32_16x16x32_bf16(
            b[JB + j][kk], a[i][kk], acc[IB + i][JB + j], 0, 0, 0);
  __builtin_amdgcn_s_setprio(0);
}

// VM: 4 = steady-state counted wait, 0 = drain (tile 62), -1 = none (last).
template <bool SA, bool SB, int VM>
__device__ __forceinline__ void tile_step(
    const unsigned short* curA, const unsigned short* curB,
    unsigned short* nxtA, unsigned short* stageB, int T,
    const float* const (&aptr)[4], const int (&alds)[4],
    float4 (&areg)[4][2], const unsigned short* Bg, int wave, int wm, int wn,
    int rA, int k0off, int k1off, bf16x8 (&a)[4][2], bf16x8 (&b)[4][2],
    f32x4 (&acc)[8][4]) {
  const int kf = (T + 1) * BK;  // fp32 element offset of next A K-tile
  // ---- P0: Mf0-3 x Nf0-1 ----
  load_a4<0>(curA, wm, rA, k0off, k1off, a);
  load_b2<0>(curB, wn, rA, k0off, k1off, b);
  if (SA) issueA2<0>(aptr, kf, areg);
  BAR();
  mfma16<0, 0>(a, b, acc);
  BAR();
  // ---- P1: Mf0-3 x Nf2-3 ----
  load_b2<2>(curB, wn, rA, k0off, k1off, b);
  if (SA) issueA2<2>(aptr, kf, areg);
  BAR();
  mfma16<0, 2>(a, b, acc);
  BAR();
  // ---- P2: Mf4-7 x Nf0-1 ----
  load_a4<4>(curA, wm, rA, k0off, k1off, a);
  if (SB) stage2(stageB, Bg, 0, T + 2, wave);
  BAR();
  mfma16<4, 0>(a, b, acc);
  BAR();
  // ---- P3: Mf4-7 x Nf2-3 ----
  if (SB) stage2(stageB, Bg, 1, T + 2, wave);
  if constexpr (VM == 4) asm volatile("s_waitcnt vmcnt(4)" ::: "memory");
  else if constexpr (VM == 0) asm volatile("s_waitcnt vmcnt(0)" ::: "memory");
  if (SA) writeA(nxtA, alds, areg);
  BAR();
  mfma16<4, 2>(a, b, acc);
  if (SA) asm volatile("s_waitcnt lgkmcnt(0)" ::: "memory");
  BAR();
}

__global__ __launch_bounds__(512, 2) void gemm_bf16_8ph(
    const float* __restrict__ x, const unsigned short* __restrict__ Bt,
    const float* __restrict__ bias, float* __restrict__ out) {
  __shared__ __align__(16) unsigned short lds[4 * BM * BK];  // 128 KiB
  unsigned short* A0 = lds;
  unsigned short* B0 = lds + 1 * BM * BK;
  unsigned short* A1 = lds + 2 * BM * BK;
  unsigned short* B1 = lds + 3 * BM * BK;

  const int tid = threadIdx.x;
  const int lane = tid & 63;
  const int wave = tid >> 6;  // 0..7
  const int wm = wave & 1;    // 2 M-waves (128 rows each)
  const int wn = wave >> 1;   // 4 N-waves (64 cols each)

  // XCD-bijective swizzle: 512 blocks, 64 contiguous output tiles per XCD.
  const int bid = blockIdx.x;
  const int wg = (bid & 7) * 64 + (bid >> 3);
  const int m0 = (wg >> 4) * BM;  // 32 m-tiles
  const int n0 = (wg & 15) * BN;  // 16 n-tiles

  f32x4 acc[8][4];
#pragma unroll
  for (int i = 0; i < 8; ++i)
#pragma unroll
    for (int j = 0; j < 4; ++j) {
      f32x4 z = {0.0f, 0.0f, 0.0f, 0.0f};
      acc[i][j] = z;
    }

  // B staging source: row tr of tile, pre-swizzled chunk (gload_lds linear).
  const int tr = tid >> 3;                    // 0..63
  const int tc = (tid & 7) ^ (tr & 7);
  const unsigned short* Bg = Bt + (size_t)(n0 + tr) * KDIM + tc * 8;

  // A reg-staging addressing: thread t=(wave,lane) covers, for c=0..3:
  //   row r = (2*wave + (c>>1))*16 + (lane&15), unswizzled chunk
  //   u = (c&1)*4 + (lane>>4). Same address shape as the verified read
  //   pattern -> conflict-free ds_write_b128. Covers 256 rows x 8 chunks.
  const float* aptr[4];
  int alds[4];
#pragma unroll
  for (int c = 0; c < 4; ++c) {
    const int r = (2 * wave + (c >> 1)) * 16 + (lane & 15);
    const int u = (c & 1) * 4 + (lane >> 4);
    aptr[c] = x + (size_t)(m0 + r) * KDIM + u * 8;
    alds[c] = r * BK + (u ^ (lane & 7)) * 8;  // r&7 == lane&7 for these rows
  }

  // ds_read fragment addressing (swizzled chunk read).
  const int rA = lane & 15;
  const int hi = lane >> 4;
  const int key = lane & 7;
  const int k0off = ((0 + hi) ^ key) * 8;
  const int k1off = ((4 + hi) ^ key) * 8;

  bf16x8 a[4][2], b[4][2];
  float4 areg[4][2];

  // Prologue: issue A(0) reads (8, oldest), B(0) (4), B(1) (4);
  // vmcnt(4): A(0)+B(0) complete, B(1) stays in flight. Then cvt+write A(0).
  issueA2<0>(aptr, 0, areg);
  issueA2<2>(aptr, 0, areg);
  stage2(B0, Bg, 0, 0, wave);
  stage2(B0, Bg, 1, 0, wave);
  stage2(B1, Bg, 0, 1, wave);
  stage2(B1, Bg, 1, 1, wave);
  asm volatile("s_waitcnt vmcnt(4)" ::: "memory");
  writeA(A0, alds, areg);
  asm volatile("s_waitcnt lgkmcnt(0)" ::: "memory");
  BAR();

  // Main loop: tiles 0..61 steady-state, unrolled by 2 for static buffers.
  for (int T = 0; T < NT - 2; T += 2) {
    tile_step<true, true, 4>(A0, B0, A1, B0, T, aptr, alds, areg, Bg, wave,
                             wm, wn, rA, k0off, k1off, a, b, acc);
    tile_step<true, true, 4>(A1, B1, A0, B1, T + 1, aptr, alds, areg, Bg,
                             wave, wm, wn, rA, k0off, k1off, a, b, acc);
  }
  // Tile 62: stage A(63) only; drain all VMEM (B(63) staged at tile 61).
  tile_step<true, false, 0>(A0, B0, A1, B0, NT - 2, aptr, alds, areg, Bg,
                            wave, wm, wn, rA, k0off, k1off, a, b, acc);
  // Tile 63: pure compute.
  tile_step<false, false, -1>(A1, B1, A0, B1, NT - 1, aptr, alds, areg, Bg,
                              wave, wm, wn, rA, k0off, k1off, a, b, acc);

  // Epilogue: lane -> m = l&15, n = (l>>4)*4 (+reg), float4 stores.
  float* zout = out + (size_t)MDIM * NDIM;
  const int ml = lane & 15;
  const int nb4 = (lane >> 4) * 4;
#pragma unroll
  for (int i = 0; i < 8; ++i) {
    int m = m0 + wm * 128 + i * 16 + ml;
    float* zrow = zout + (size_t)m * NDIM;
    float* srow = out + (size_t)m * NDIM;
#pragma unroll
    for (int j = 0; j < 4; ++j) {
      int n = n0 + wn * 64 + j * 16 + nb4;
      float4 bv = *(const float4*)&bias[n];
      f32x4 v = acc[i][j];
      float4 z, s;
      z.x = v[0] + bv.x; z.y = v[1] + bv.y; z.z = v[2] + bv.z; z.w = v[3] + bv.w;
      s.x = (z.x >= 0.0f) ? 1.0f : -1.0f;
      s.y = (z.y >= 0.0f) ? 1.0f : -1.0f;
      s.z = (z.z >= 0.0f) ? 1.0f : -1.0f;
      s.w = (z.w >= 0.0f) ? 1.0f : -1.0f;
      *(float4*)&zrow[n] = z;
      *(float4*)&srow[n] = s;
    }
  }
}

// ---------------- fallback GEMM (128^2, fp32 inputs, no workspace) ----------
__device__ __forceinline__ void mfma_step128(const unsigned short* As,
                                             const unsigned short* Bs,
                                             f32x4 acc[4][4], int lane, int wm,
                                             int wn) {
  const int rA = lane & 15;
  const int key = lane & 7;
#pragma unroll
  for (int kk = 0; kk < 2; ++kk) {
    const int koff = ((kk * 4 + (lane >> 4)) ^ key) * 8;
    bf16x8 a[4], b[4];
#pragma unroll
    for (int i = 0; i < 4; ++i) {
      a[i] = *(const bf16x8*)(As + (size_t)(wm * 64 + i * 16 + rA) * 64 + koff);
      b[i] = *(const bf16x8*)(Bs + (size_t)(wn * 64 + i * 16 + rA) * 64 + koff);
    }
#pragma unroll
    for (int i = 0; i < 4; ++i)
#pragma unroll
      for (int j = 0; j < 4; ++j)
        acc[i][j] = __builtin_amdgcn_mfma_f32_16x16x32_bf16(b[j], a[i],
                                                            acc[i][j], 0, 0, 0);
  }
}

__global__ __launch_bounds__(256) void gemm_bf16_nows(
    const float* __restrict__ x, const float* __restrict__ W,
    const float* __restrict__ bias, float* __restrict__ out) {
  __shared__ __align__(16) unsigned short As[128 * 64];
  __shared__ __align__(16) unsigned short Bs[128 * 64];

  const int tid = threadIdx.x;
  const int lane = tid & 63;
  const int wave = tid >> 6;
  const int wm = wave & 1;
  const int wn = wave >> 1;
  const int m0 = blockIdx.y * 128;
  const int n0 = blockIdx.x * 128;

  f32x4 acc[4][4];
#pragma unroll
  for (int i = 0; i < 4; ++i)
#pragma unroll
    for (int j = 0; j < 4; ++j) {
      f32x4 z = {0.0f, 0.0f, 0.0f, 0.0f};
      acc[i][j] = z;
    }

  for (int k0 = 0; k0 < KDIM; k0 += 64) {
    {
      const int kc = (tid & 15) * 4;
      const int cb = kc >> 3;
      const int wi = kc & 7;
      const int rowb = tid >> 4;
#pragma unroll
      for (int r = 0; r < 8; ++r) {
        int row = rowb + 16 * r;
        float4 v = *(const float4*)&x[(size_t)(m0 + row) * KDIM + k0 + kc];
        uint2 pk;
        pk.x = f2bf(v.x) | (f2bf(v.y) << 16);
        pk.y = f2bf(v.z) | (f2bf(v.w) << 16);
        *(uint2*)&As[row * 64 + ((cb ^ (row & 7)) * 8) + wi] = pk;
      }
    }
    {
      const int nc = (tid & 31) * 4;
      const int kb = tid >> 5;
#pragma unroll
      for (int r = 0; r < 8; ++r) {
        int krow = kb + 8 * r;
        int cb = krow >> 3, wi = krow & 7;
        float4 v = *(const float4*)&W[(size_t)(k0 + krow) * NDIM + n0 + nc];
        Bs[(nc + 0) * 64 + ((cb ^ ((nc + 0) & 7)) * 8) + wi] = (unsigned short)f2bf(v.x);
        Bs[(nc + 1) * 64 + ((cb ^ ((nc + 1) & 7)) * 8) + wi] = (unsigned short)f2bf(v.y);
        Bs[(nc + 2) * 64 + ((cb ^ ((nc + 2) & 7)) * 8) + wi] = (unsigned short)f2bf(v.z);
        Bs[(nc + 3) * 64 + ((cb ^ ((nc + 3) & 7)) * 8) + wi] = (unsigned short)f2bf(v.w);
      }
    }
    __syncthreads();
    mfma_step128(As, Bs, acc, lane, wm, wn);
    __syncthreads();
  }

  float* zout = out + (size_t)MDIM * NDIM;
  const int ml = lane & 15;
  const int nb4 = (lane >> 4) * 4;
#pragma unroll
  for (int i = 0; i < 4; ++i) {
    int m = m0 + wm * 64 + i * 16 + ml;
    float* zrow = zout + (size_t)m * NDIM;
    float* srow = out + (size_t)m * NDIM;
#pragma unroll
    for (int j = 0; j < 4; ++j) {
      int n = n0 + wn * 64 + j * 16 + nb4;
      float4 bv = *(const float4*)&bias[n];
      f32x4 v = acc[i][j];
      float4 z, s;
      z.x = v[0] + bv.x; z.y = v[1] + bv.y; z.z = v[2] + bv.z; z.w = v[3] + bv.w;
      s.x = (z.x >= 0.0f) ? 1.0f : -1.0f;
      s.y = (z.y >= 0.0f) ? 1.0f : -1.0f;
      s.z = (z.z >= 0.0f) ? 1.0f : -1.0f;
      s.w = (z.w >= 0.0f) ? 1.0f : -1.0f;
      *(float4*)&zrow[n] = z;
      *(float4*)&srow[n] = s;
    }
  }
}

// ---------------- launcher ----------------
extern "C" void kernel_launch(void* const* d_in, const int* in_sizes, int n_in,
                              void* d_out, int out_size, void* d_ws,
                              size_t ws_size, hipStream_t stream) {
  (void)in_sizes; (void)n_in; (void)out_size;
  const float* x = (const float*)d_in[0];
  const float* W = (const float*)d_in[1];
  const float* b = (const float*)d_in[2];
  float* out = (float*)d_out;

  const size_t wt_elems = (size_t)KDIM * NDIM;
  const size_t need = wt_elems * sizeof(unsigned short);

  if (ws_size >= need) {
    unsigned short* wt = (unsigned short*)d_ws;
    cvt_w<<<CVT_W_BLOCKS, 256, 0, stream>>>(W, wt);
    gemm_bf16_8ph<<<(MDIM / BM) * (NDIM / BN), 512, 0, stream>>>(x, wt, b, out);
  } else {
    dim3 fgrid(NDIM / 128, MDIM / 128);
    gemm_bf16_nows<<<fgrid, 256, 0, stream>>>(x, W, b, out);
  }
}

// Round 3
// 750.727 us; speedup vs baseline: 1.0366x; 1.0366x over previous
//
#include <hip/hip_runtime.h>
#include <stdint.h>

// Problem dims (fixed): x [M,K] fp32, W [K,N] fp32 ternary, b [N] fp32.
// out = concat( sign(z) [M,N], z [M,N] ), z = x@W + b, all fp32.
#define MDIM 8192
#define NDIM 4096
#define KDIM 4096

// 8-phase GEMM geometry (256x256 tile, BK=64, 8 waves 2Mx4N)
#define BM 256
#define BN 256
#define BK 64
#define NT (KDIM / BK)  // 64 K-tiles

#define CVT_W_BLOCKS 4096   // (N/64)*(K/64)

typedef __bf16 bf16x8 __attribute__((ext_vector_type(8)));
typedef float f32x4 __attribute__((ext_vector_type(4)));

#define GPTR(p) ((const __attribute__((address_space(1))) void*)(p))
#define LPTR(p) ((__attribute__((address_space(3))) void*)(p))

// Raw barrier with compiler memory fence.
#define BAR() asm volatile("s_barrier" ::: "memory")
// Scheduler fence (rule #18): pin register-only ops after explicit waitcnts.
#define SCHED_FENCE() __builtin_amdgcn_sched_barrier(0)

__device__ __forceinline__ uint32_t f2bf(float f) {
  union { float f; uint32_t u; } c; c.f = f;
  uint32_t u = c.u;
  u += 0x7fffu + ((u >> 16) & 1u);   // RTNE
  return u >> 16;
}

// packed f32x2 -> bf16x2 (RTNE). MUST be volatile: non-volatile register-only
// asm gets hoisted by the scheduler toward its VMEM inputs, dragging a
// compiler-inserted early vmcnt that drains the pipeline (round-2 regression:
// MfmaUtil 46->22). volatile pins it after our counted s_waitcnt vmcnt(4).
__device__ __forceinline__ uint32_t cvtpk(float lo, float hi) {
  uint32_t r;
  asm volatile("v_cvt_pk_bf16_f32 %0, %1, %2" : "=v"(r) : "v"(lo), "v"(hi));
  return r;
}

// ---------------- W conversion kernel (W-part of verified cvt_fused) --------
// W [K,N] -> Wt [N,K] bf16, 64x64 LDS transpose tile (ld=37).
__global__ __launch_bounds__(256) void cvt_w(const float* __restrict__ W,
                                             unsigned short* __restrict__ Wt) {
  __shared__ uint32_t T[64][37];
  const int wb = blockIdx.x;
  const int t = threadIdx.x;
  const int n0 = (wb & 63) * 64;
  const int k0 = (wb >> 6) * 64;
  const int nl = t & 63;
  const int kpb = t >> 6;  // 0..3
#pragma unroll
  for (int i = 0; i < 8; ++i) {
    int kp = kpb + 4 * i;  // pair of k rows
    int k = 2 * kp;
    float v0 = W[(size_t)(k0 + k) * NDIM + n0 + nl];
    float v1 = W[(size_t)(k0 + k + 1) * NDIM + n0 + nl];
    T[nl][kp] = f2bf(v0) | (f2bf(v1) << 16);
  }
  __syncthreads();
  const int ch = t & 7;   // 16B chunk (8 k)
  const int nb = t >> 3;  // 0..31
#pragma unroll
  for (int h = 0; h < 2; ++h) {
    int n = nb + 32 * h;
    uint4 v;
    v.x = T[n][ch * 4 + 0];
    v.y = T[n][ch * 4 + 1];
    v.z = T[n][ch * 4 + 2];
    v.w = T[n][ch * 4 + 3];
    *(uint4*)&Wt[(size_t)(n0 + n) * KDIM + k0 + ch * 8] = v;
  }
}

// ---------------- 8-phase 256x256 GEMM, A reg-staged from fp32 x ------------
// LDS layout per operand tile: [256 rows][64 K] bf16; chunk c of row r stored
// at chunk position c ^ (r&7) (zero-conflict ds_read_b128, verified).
// B: global_load_lds with pre-swizzled global source (rule 21, verified).
// A: reg-staged from fp32 x: issue 8 global_load_dwordx4 at P0/P1, then at P3
//    (after vmcnt) v_cvt_pk_bf16_f32 + 4x ds_write_b128 using the SAME
//    lane->(row,chunk) shape as the verified read pattern (0 conflicts).
//
// Per tile T (steady):
//  P0: ds_reads A-frags 0-3 + B-frags 0-1 | issue A(T+1) reads c=0,1
//  P1: ds_reads B-frags 2-3               | issue A(T+1) reads c=2,3
//  P2: ds_reads A-frags 4-7               | gload_lds B(T+2) half0
//  P3: gload_lds B(T+2) half1 | vmcnt(4)  -> completes A(T+1) reads AND
//      publishes B(T+1), keeps B(T+2)(4) in flight | cvt+ds_write A(T+1)
//      | BAR | mfma | lgkmcnt(0) | BAR  (publishes A(T+1))
// Buffer liveness: nxtA last READ at tile T-1 P2 (2+ barriers before writes);
// stageB (=curB buffer) last read at P1, staged at P2/P3 of same tile.

__device__ __forceinline__ void stage2(unsigned short* dst,
                                       const unsigned short* G, int half,
                                       int tile, int wave) {
#pragma unroll
  for (int i = 0; i < 2; ++i) {
    const int rb = half * 128 + i * 64;  // 64 rows per instruction (512 thr)
    __builtin_amdgcn_global_load_lds(
        GPTR(G + (size_t)rb * KDIM + (size_t)tile * 64),
        LPTR(dst + (rb + wave * 8) * BK), 16, 0, 0);
  }
}

// Issue 2 of the 4 A-chunk reads (fp32, 2 float4 each).
template <int C0>
__device__ __forceinline__ void issueA2(const float* const (&aptr)[4], int kf,
                                        float4 (&areg)[4][2]) {
#pragma unroll
  for (int c = C0; c < C0 + 2; ++c) {
    areg[c][0] = *(const float4*)(aptr[c] + kf);
    areg[c][1] = *(const float4*)(aptr[c] + kf + 4);
  }
}

// Convert + swizzled LDS write of the staged A tile. Caller must have
// executed the counted vmcnt covering the areg loads (volatile cvtpk keeps
// the conversions ordered after it).
__device__ __forceinline__ void writeA(unsigned short* nxtA,
                                       const int (&alds)[4],
                                       const float4 (&areg)[4][2]) {
#pragma unroll
  for (int c = 0; c < 4; ++c) {
    uint4 v;
    v.x = cvtpk(areg[c][0].x, areg[c][0].y);
    v.y = cvtpk(areg[c][0].z, areg[c][0].w);
    v.z = cvtpk(areg[c][1].x, areg[c][1].y);
    v.w = cvtpk(areg[c][1].z, areg[c][1].w);
    *(uint4*)(nxtA + alds[c]) = v;
  }
}

template <int IB>
__device__ __forceinline__ void load_a4(const unsigned short* buf, int wm,
                                        int rA, int k0off, int k1off,
                                        bf16x8 (&a)[4][2]) {
#pragma unroll
  for (int i = 0; i < 4; ++i) {
    const unsigned short* p = buf + (size_t)(wm * 128 + (IB + i) * 16 + rA) * BK;
    a[i][0] = *(const bf16x8*)(p + k0off);
    a[i][1] = *(const bf16x8*)(p + k1off);
  }
}

template <int JB>
__device__ __forceinline__ void load_b2(const unsigned short* buf, int wn,
                                        int rA, int k0off, int k1off,
                                        bf16x8 (&b)[4][2]) {
#pragma unroll
  for (int j = 0; j < 2; ++j) {
    const unsigned short* p = buf + (size_t)(wn * 64 + (JB + j) * 16 + rA) * BK;
    b[JB + j][0] = *(const bf16x8*)(p + k0off);
    b[JB + j][1] = *(const bf16x8*)(p + k1off);
  }
}

// OPERAND SWAP (verified): acc = mfma(b, a, acc) -> lane l: m = l&15,
// n = (l>>4)*4 + reg  => float4 epilogue stores along n.
template <int IB, int JB>
__device__ __forceinline__ void mfma16(const bf16x8 (&a)[4][2],
                                       const bf16x8 (&b)[4][2],
                                       f32x4 (&acc)[8][4]) {
  __builtin_amdgcn_s_setprio(1);
#pragma unroll
  for (int i = 0; i < 4; ++i)
#pragma unroll
    for (int j = 0; j < 2; ++j)
#pragma unroll
      for (int kk = 0; kk < 2; ++kk)
        acc[IB + i][JB + j] = __builtin_amdgcn_mfma_f32_16x16x32_bf16(
            b[JB + j][kk], a[i][kk], acc[IB + i][JB + j], 0, 0, 0);
  __builtin_amdgcn_s_setprio(0);
}

// VM: 4 = steady-state counted wait, 0 = drain (tile 62), -1 = none (last).
template <bool SA, bool SB, int VM>
__device__ __forceinline__ void tile_step(
    const unsigned short* curA, const unsigned short* curB,
    unsigned short* nxtA, unsigned short* stageB, int T,
    const float* const (&aptr)[4], const int (&alds)[4],
    float4 (&areg)[4][2], const unsigned short* Bg, int wave, int wm, int wn,
    int rA, int k0off, int k1off, bf16x8 (&a)[4][2], bf16x8 (&b)[4][2],
    f32x4 (&acc)[8][4]) {
  const int kf = (T + 1) * BK;  // fp32 element offset of next A K-tile
  // ---- P0: Mf0-3 x Nf0-1 ----
  load_a4<0>(curA, wm, rA, k0off, k1off, a);
  load_b2<0>(curB, wn, rA, k0off, k1off, b);
  if (SA) issueA2<0>(aptr, kf, areg);
  BAR();
  mfma16<0, 0>(a, b, acc);
  BAR();
  // ---- P1: Mf0-3 x Nf2-3 ----
  load_b2<2>(curB, wn, rA, k0off, k1off, b);
  if (SA) issueA2<2>(aptr, kf, areg);
  BAR();
  mfma16<0, 2>(a, b, acc);
  BAR();
  // ---- P2: Mf4-7 x Nf0-1 ----
  load_a4<4>(curA, wm, rA, k0off, k1off, a);
  if (SB) stage2(stageB, Bg, 0, T + 2, wave);
  BAR();
  mfma16<4, 0>(a, b, acc);
  BAR();
  // ---- P3: Mf4-7 x Nf2-3 ----
  if (SB) stage2(stageB, Bg, 1, T + 2, wave);
  if constexpr (VM == 4) {
    asm volatile("s_waitcnt vmcnt(4)" ::: "memory");
    SCHED_FENCE();
  } else if constexpr (VM == 0) {
    asm volatile("s_waitcnt vmcnt(0)" ::: "memory");
    SCHED_FENCE();
  }
  if (SA) writeA(nxtA, alds, areg);
  BAR();
  mfma16<4, 2>(a, b, acc);
  if (SA) asm volatile("s_waitcnt lgkmcnt(0)" ::: "memory");
  BAR();
}

__global__ __launch_bounds__(512, 2) void gemm_bf16_8ph(
    const float* __restrict__ x, const unsigned short* __restrict__ Bt,
    const float* __restrict__ bias, float* __restrict__ out) {
  __shared__ __align__(16) unsigned short lds[4 * BM * BK];  // 128 KiB
  unsigned short* A0 = lds;
  unsigned short* B0 = lds + 1 * BM * BK;
  unsigned short* A1 = lds + 2 * BM * BK;
  unsigned short* B1 = lds + 3 * BM * BK;

  const int tid = threadIdx.x;
  const int lane = tid & 63;
  const int wave = tid >> 6;  // 0..7
  const int wm = wave & 1;    // 2 M-waves (128 rows each)
  const int wn = wave >> 1;   // 4 N-waves (64 cols each)

  // XCD-bijective swizzle: 512 blocks, 64 contiguous output tiles per XCD.
  const int bid = blockIdx.x;
  const int wg = (bid & 7) * 64 + (bid >> 3);
  const int m0 = (wg >> 4) * BM;  // 32 m-tiles
  const int n0 = (wg & 15) * BN;  // 16 n-tiles

  f32x4 acc[8][4];
#pragma unroll
  for (int i = 0; i < 8; ++i)
#pragma unroll
    for (int j = 0; j < 4; ++j) {
      f32x4 z = {0.0f, 0.0f, 0.0f, 0.0f};
      acc[i][j] = z;
    }

  // B staging source: row tr of tile, pre-swizzled chunk (gload_lds linear).
  const int tr = tid >> 3;                    // 0..63
  const int tc = (tid & 7) ^ (tr & 7);
  const unsigned short* Bg = Bt + (size_t)(n0 + tr) * KDIM + tc * 8;

  // A reg-staging addressing: thread t=(wave,lane) covers, for c=0..3:
  //   row r = (2*wave + (c>>1))*16 + (lane&15), unswizzled chunk
  //   u = (c&1)*4 + (lane>>4). Same address shape as the verified read
  //   pattern -> conflict-free ds_write_b128. Covers 256 rows x 8 chunks.
  const float* aptr[4];
  int alds[4];
#pragma unroll
  for (int c = 0; c < 4; ++c) {
    const int r = (2 * wave + (c >> 1)) * 16 + (lane & 15);
    const int u = (c & 1) * 4 + (lane >> 4);
    aptr[c] = x + (size_t)(m0 + r) * KDIM + u * 8;
    alds[c] = r * BK + (u ^ (lane & 7)) * 8;  // r&7 == lane&7 for these rows
  }

  // ds_read fragment addressing (swizzled chunk read).
  const int rA = lane & 15;
  const int hi = lane >> 4;
  const int key = lane & 7;
  const int k0off = ((0 + hi) ^ key) * 8;
  const int k1off = ((4 + hi) ^ key) * 8;

  bf16x8 a[4][2], b[4][2];
  float4 areg[4][2];

  // Prologue: issue A(0) reads (8, oldest), B(0) (4), B(1) (4);
  // vmcnt(4): A(0)+B(0) complete, B(1) stays in flight. Then cvt+write A(0).
  issueA2<0>(aptr, 0, areg);
  issueA2<2>(aptr, 0, areg);
  stage2(B0, Bg, 0, 0, wave);
  stage2(B0, Bg, 1, 0, wave);
  stage2(B1, Bg, 0, 1, wave);
  stage2(B1, Bg, 1, 1, wave);
  asm volatile("s_waitcnt vmcnt(4)" ::: "memory");
  SCHED_FENCE();
  writeA(A0, alds, areg);
  asm volatile("s_waitcnt lgkmcnt(0)" ::: "memory");
  BAR();

  // Main loop: tiles 0..61 steady-state, unrolled by 2 for static buffers.
  for (int T = 0; T < NT - 2; T += 2) {
    tile_step<true, true, 4>(A0, B0, A1, B0, T, aptr, alds, areg, Bg, wave,
                             wm, wn, rA, k0off, k1off, a, b, acc);
    tile_step<true, true, 4>(A1, B1, A0, B1, T + 1, aptr, alds, areg, Bg,
                             wave, wm, wn, rA, k0off, k1off, a, b, acc);
  }
  // Tile 62: stage A(63) only; drain all VMEM (B(63) staged at tile 61).
  tile_step<true, false, 0>(A0, B0, A1, B0, NT - 2, aptr, alds, areg, Bg,
                            wave, wm, wn, rA, k0off, k1off, a, b, acc);
  // Tile 63: pure compute.
  tile_step<false, false, -1>(A1, B1, A0, B1, NT - 1, aptr, alds, areg, Bg,
                              wave, wm, wn, rA, k0off, k1off, a, b, acc);

  // Epilogue: lane -> m = l&15, n = (l>>4)*4 (+reg), float4 stores.
  float* zout = out + (size_t)MDIM * NDIM;
  const int ml = lane & 15;
  const int nb4 = (lane >> 4) * 4;
#pragma unroll
  for (int i = 0; i < 8; ++i) {
    int m = m0 + wm * 128 + i * 16 + ml;
    float* zrow = zout + (size_t)m * NDIM;
    float* srow = out + (size_t)m * NDIM;
#pragma unroll
    for (int j = 0; j < 4; ++j) {
      int n = n0 + wn * 64 + j * 16 + nb4;
      float4 bv = *(const float4*)&bias[n];
      f32x4 v = acc[i][j];
      float4 z, s;
      z.x = v[0] + bv.x; z.y = v[1] + bv.y; z.z = v[2] + bv.z; z.w = v[3] + bv.w;
      s.x = (z.x >= 0.0f) ? 1.0f : -1.0f;
      s.y = (z.y >= 0.0f) ? 1.0f : -1.0f;
      s.z = (z.z >= 0.0f) ? 1.0f : -1.0f;
      s.w = (z.w >= 0.0f) ? 1.0f : -1.0f;
      *(float4*)&zrow[n] = z;
      *(float4*)&srow[n] = s;
    }
  }
}

// ---------------- fallback GEMM (128^2, fp32 inputs, no workspace) ----------
__device__ __forceinline__ void mfma_step128(const unsigned short* As,
                                             const unsigned short* Bs,
                                             f32x4 acc[4][4], int lane, int wm,
                                             int wn) {
  const int rA = lane & 15;
  const int key = lane & 7;
#pragma unroll
  for (int kk = 0; kk < 2; ++kk) {
    const int koff = ((kk * 4 + (lane >> 4)) ^ key) * 8;
    bf16x8 a[4], b[4];
#pragma unroll
    for (int i = 0; i < 4; ++i) {
      a[i] = *(const bf16x8*)(As + (size_t)(wm * 64 + i * 16 + rA) * 64 + koff);
      b[i] = *(const bf16x8*)(Bs + (size_t)(wn * 64 + i * 16 + rA) * 64 + koff);
    }
#pragma unroll
    for (int i = 0; i < 4; ++i)
#pragma unroll
      for (int j = 0; j < 4; ++j)
        acc[i][j] = __builtin_amdgcn_mfma_f32_16x16x32_bf16(b[j], a[i],
                                                            acc[i][j], 0, 0, 0);
  }
}

__global__ __launch_bounds__(256) void gemm_bf16_nows(
    const float* __restrict__ x, const float* __restrict__ W,
    const float* __restrict__ bias, float* __restrict__ out) {
  __shared__ __align__(16) unsigned short As[128 * 64];
  __shared__ __align__(16) unsigned short Bs[128 * 64];

  const int tid = threadIdx.x;
  const int lane = tid & 63;
  const int wave = tid >> 6;
  const int wm = wave & 1;
  const int wn = wave >> 1;
  const int m0 = blockIdx.y * 128;
  const int n0 = blockIdx.x * 128;

  f32x4 acc[4][4];
#pragma unroll
  for (int i = 0; i < 4; ++i)
#pragma unroll
    for (int j = 0; j < 4; ++j) {
      f32x4 z = {0.0f, 0.0f, 0.0f, 0.0f};
      acc[i][j] = z;
    }

  for (int k0 = 0; k0 < KDIM; k0 += 64) {
    {
      const int kc = (tid & 15) * 4;
      const int cb = kc >> 3;
      const int wi = kc & 7;
      const int rowb = tid >> 4;
#pragma unroll
      for (int r = 0; r < 8; ++r) {
        int row = rowb + 16 * r;
        float4 v = *(const float4*)&x[(size_t)(m0 + row) * KDIM + k0 + kc];
        uint2 pk;
        pk.x = f2bf(v.x) | (f2bf(v.y) << 16);
        pk.y = f2bf(v.z) | (f2bf(v.w) << 16);
        *(uint2*)&As[row * 64 + ((cb ^ (row & 7)) * 8) + wi] = pk;
      }
    }
    {
      const int nc = (tid & 31) * 4;
      const int kb = tid >> 5;
#pragma unroll
      for (int r = 0; r < 8; ++r) {
        int krow = kb + 8 * r;
        int cb = krow >> 3, wi = krow & 7;
        float4 v = *(const float4*)&W[(size_t)(k0 + krow) * NDIM + n0 + nc];
        Bs[(nc + 0) * 64 + ((cb ^ ((nc + 0) & 7)) * 8) + wi] = (unsigned short)f2bf(v.x);
        Bs[(nc + 1) * 64 + ((cb ^ ((nc + 1) & 7)) * 8) + wi] = (unsigned short)f2bf(v.y);
        Bs[(nc + 2) * 64 + ((cb ^ ((nc + 2) & 7)) * 8) + wi] = (unsigned short)f2bf(v.z);
        Bs[(nc + 3) * 64 + ((cb ^ ((nc + 3) & 7)) * 8) + wi] = (unsigned short)f2bf(v.w);
      }
    }
    __syncthreads();
    mfma_step128(As, Bs, acc, lane, wm, wn);
    __syncthreads();
  }

  float* zout = out + (size_t)MDIM * NDIM;
  const int ml = lane & 15;
  const int nb4 = (lane >> 4) * 4;
#pragma unroll
  for (int i = 0; i < 4; ++i) {
    int m = m0 + wm * 64 + i * 16 + ml;
    float* zrow = zout + (size_t)m * NDIM;
    float* srow = out + (size_t)m * NDIM;
#pragma unroll
    for (int j = 0; j < 4; ++j) {
      int n = n0 + wn * 64 + j * 16 + nb4;
      float4 bv = *(const float4*)&bias[n];
      f32x4 v = acc[i][j];
      float4 z, s;
      z.x = v[0] + bv.x; z.y = v[1] + bv.y; z.z = v[2] + bv.z; z.w = v[3] + bv.w;
      s.x = (z.x >= 0.0f) ? 1.0f : -1.0f;
      s.y = (z.y >= 0.0f) ? 1.0f : -1.0f;
      s.z = (z.z >= 0.0f) ? 1.0f : -1.0f;
      s.w = (z.w >= 0.0f) ? 1.0f : -1.0f;
      *(float4*)&zrow[n] = z;
      *(float4*)&srow[n] = s;
    }
  }
}

// ---------------- launcher ----------------
extern "C" void kernel_launch(void* const* d_in, const int* in_sizes, int n_in,
                              void* d_out, int out_size, void* d_ws,
                              size_t ws_size, hipStream_t stream) {
  (void)in_sizes; (void)n_in; (void)out_size;
  const float* x = (const float*)d_in[0];
  const float* W = (const float*)d_in[1];
  const float* b = (const float*)d_in[2];
  float* out = (float*)d_out;

  const size_t wt_elems = (size_t)KDIM * NDIM;
  const size_t need = wt_elems * sizeof(unsigned short);

  if (ws_size >= need) {
    unsigned short* wt = (unsigned short*)d_ws;
    cvt_w<<<CVT_W_BLOCKS, 256, 0, stream>>>(W, wt);
    gemm_bf16_8ph<<<(MDIM / BM) * (NDIM / BN), 512, 0, stream>>>(x, wt, b, out);
  } else {
    dim3 fgrid(NDIM / 128, MDIM / 128);
    gemm_bf16_nows<<<fgrid, 256, 0, stream>>>(x, W, b, out);
  }
}

// Round 4
// 625.607 us; speedup vs baseline: 1.2439x; 1.2000x over previous
//
#include <hip/hip_runtime.h>
#include <stdint.h>

// Problem dims (fixed): x [M,K] fp32, W [K,N] fp32 ternary, b [N] fp32.
// out = concat( sign(z) [M,N], z [M,N] ), z = x@W + b, all fp32.
#define MDIM 8192
#define NDIM 4096
#define KDIM 4096

// 8-phase GEMM geometry (256x256 tile, BK=64, 8 waves 2Mx4N)
#define BM 256
#define BN 256
#define BK 64
#define NT (KDIM / BK)  // 64 K-tiles

#define CVT_X_BLOCKS 16384  // M*K/(256*8)
#define CVT_W_BLOCKS 4096   // (N/64)*(K/64)

typedef __bf16 bf16x8 __attribute__((ext_vector_type(8)));
typedef float f32x4 __attribute__((ext_vector_type(4)));

#define GPTR(p) ((const __attribute__((address_space(1))) void*)(p))
#define LPTR(p) ((__attribute__((address_space(3))) void*)(p))

// Raw barrier with compiler memory fence.
#define BAR() asm volatile("s_barrier" ::: "memory")

__device__ __forceinline__ uint32_t f2bf(float f) {
  union { float f; uint32_t u; } c; c.f = f;
  uint32_t u = c.u;
  u += 0x7fffu + ((u >> 16) & 1u);   // RTNE (NaN irrelevant for this data)
  return u >> 16;
}

// ---------------- fused conversion kernel (round-1 verified) ----------------
// Blocks [0, CVT_X_BLOCKS):  x fp32 -> bf16, 8 elems/thread, coalesced.
// Blocks [CVT_X_BLOCKS, +CVT_W_BLOCKS): W [K,N] -> Wt [N,K] bf16, 64x64 LDS
// transpose tile (ld=37).
__global__ __launch_bounds__(256) void cvt_fused(const float* __restrict__ x,
                                                 const float* __restrict__ W,
                                                 unsigned short* __restrict__ xb,
                                                 unsigned short* __restrict__ Wt) {
  __shared__ uint32_t T[64][37];
  const int bid = blockIdx.x;
  const int t = threadIdx.x;
  if (bid < CVT_X_BLOCKS) {
    size_t i = ((size_t)bid * 256 + t) * 8;
    const float4* p = (const float4*)(x + i);
    float4 a = p[0], b = p[1];
    uint4 r;
    r.x = f2bf(a.x) | (f2bf(a.y) << 16);
    r.y = f2bf(a.z) | (f2bf(a.w) << 16);
    r.z = f2bf(b.x) | (f2bf(b.y) << 16);
    r.w = f2bf(b.z) | (f2bf(b.w) << 16);
    *(uint4*)(xb + i) = r;
  } else {
    const int wb = bid - CVT_X_BLOCKS;
    const int n0 = (wb & 63) * 64;
    const int k0 = (wb >> 6) * 64;
    const int nl = t & 63;
    const int kpb = t >> 6;  // 0..3
#pragma unroll
    for (int i = 0; i < 8; ++i) {
      int kp = kpb + 4 * i;  // pair of k rows
      int k = 2 * kp;
      float v0 = W[(size_t)(k0 + k) * NDIM + n0 + nl];
      float v1 = W[(size_t)(k0 + k + 1) * NDIM + n0 + nl];
      T[nl][kp] = f2bf(v0) | (f2bf(v1) << 16);
    }
    __syncthreads();
    const int ch = t & 7;   // 16B chunk (8 k)
    const int nb = t >> 3;  // 0..31
#pragma unroll
    for (int h = 0; h < 2; ++h) {
      int n = nb + 32 * h;
      uint4 v;
      v.x = T[n][ch * 4 + 0];
      v.y = T[n][ch * 4 + 1];
      v.z = T[n][ch * 4 + 2];
      v.w = T[n][ch * 4 + 3];
      *(uint4*)&Wt[(size_t)(n0 + n) * KDIM + k0 + ch * 8] = v;
    }
  }
}

// ---------------- 8-phase 256x256 GEMM (all-gload_lds, deep pipeline) -------
// LDS layout per operand tile: [256 rows][64 K] bf16; chunk c of row r stored
// at chunk position c ^ (r&7) (zero-conflict ds_read_b128, verified).
// Staging: global_load_lds with pre-swizzled global source (rule 21).
//
// Schedule v2 (vs round-1): BOTH operands of tile T+2 staged at tile T's
// P2/P3 (overwrite-behind into the CURRENT buffers, since (T+2)&1 == T&1),
// one counted vmcnt(8) per tile at P3 = 2 full tiles (8 loads) in flight.
// Every half-tile gets 4-6 phases of latency cover (round-1's A had only 2-3,
// stalling P3's wait on L3 latency every tile).
//
// Stage halves match consumption order: half h covers rows {h*64..h*64+63,
// 128+h*64..128+h*64+63}. A rows 0-63/128-191 (frags 0-3) last read at P0 ->
// h0 staged at P2 (2 barriers later); A rows 64-127/192-255 (frags 4-7) last
// read at P2 -> h1 staged at P3 (1 barrier later). All B reads finish by P1.

__device__ __forceinline__ void stage2(unsigned short* dst,
                                       const unsigned short* G, int half,
                                       int tile, int wave) {
#pragma unroll
  for (int i = 0; i < 2; ++i) {
    const int rb = i * 128 + half * 64;  // 64 rows per instruction (512 thr)
    __builtin_amdgcn_global_load_lds(
        GPTR(G + (size_t)rb * KDIM + (size_t)tile * 64),
        LPTR(dst + (rb + wave * 8) * BK), 16, 0, 0);
  }
}

template <int IB>
__device__ __forceinline__ void load_a4(const unsigned short* buf, int wm,
                                        int rA, int k0off, int k1off,
                                        bf16x8 (&a)[4][2]) {
#pragma unroll
  for (int i = 0; i < 4; ++i) {
    const unsigned short* p = buf + (size_t)(wm * 128 + (IB + i) * 16 + rA) * BK;
    a[i][0] = *(const bf16x8*)(p + k0off);
    a[i][1] = *(const bf16x8*)(p + k1off);
  }
}

template <int JB>
__device__ __forceinline__ void load_b2(const unsigned short* buf, int wn,
                                        int rA, int k0off, int k1off,
                                        bf16x8 (&b)[4][2]) {
#pragma unroll
  for (int j = 0; j < 2; ++j) {
    const unsigned short* p = buf + (size_t)(wn * 64 + (JB + j) * 16 + rA) * BK;
    b[JB + j][0] = *(const bf16x8*)(p + k0off);
    b[JB + j][1] = *(const bf16x8*)(p + k1off);
  }
}

// OPERAND SWAP (verified): acc = mfma(b, a, acc) -> lane l: m = l&15,
// n = (l>>4)*4 + reg  => float4 epilogue stores along n.
template <int IB, int JB>
__device__ __forceinline__ void mfma16(const bf16x8 (&a)[4][2],
                                       const bf16x8 (&b)[4][2],
                                       f32x4 (&acc)[8][4]) {
  __builtin_amdgcn_s_setprio(1);
#pragma unroll
  for (int i = 0; i < 4; ++i)
#pragma unroll
    for (int j = 0; j < 2; ++j)
#pragma unroll
      for (int kk = 0; kk < 2; ++kk)
        acc[IB + i][JB + j] = __builtin_amdgcn_mfma_f32_16x16x32_bf16(
            b[JB + j][kk], a[i][kk], acc[IB + i][JB + j], 0, 0, 0);
  __builtin_amdgcn_s_setprio(0);
}

// S: stage tile T+2. VM: 8 = steady counted wait, 0 = drain (tile 62),
// -1 = none (tile 63).
template <bool S, int VM>
__device__ __forceinline__ void tile_step(
    unsigned short* curA, unsigned short* curB, int T,
    const unsigned short* Ag, const unsigned short* Bg, int wave, int wm,
    int wn, int rA, int k0off, int k1off, bf16x8 (&a)[4][2], bf16x8 (&b)[4][2],
    f32x4 (&acc)[8][4]) {
  // ---- P0: Mf0-3 x Nf0-1 ----
  load_a4<0>(curA, wm, rA, k0off, k1off, a);
  load_b2<0>(curB, wn, rA, k0off, k1off, b);
  BAR();
  mfma16<0, 0>(a, b, acc);
  BAR();
  // ---- P1: Mf0-3 x Nf2-3 ----
  load_b2<2>(curB, wn, rA, k0off, k1off, b);
  BAR();
  mfma16<0, 2>(a, b, acc);
  BAR();
  // ---- P2: Mf4-7 x Nf0-1 ----
  load_a4<4>(curA, wm, rA, k0off, k1off, a);
  if (S) {
    stage2(curB, Bg, 0, T + 2, wave);  // B rows 0-63,128-191 (read <= P1)
    stage2(curA, Ag, 0, T + 2, wave);  // A rows 0-63,128-191 (read at P0)
  }
  BAR();
  mfma16<4, 0>(a, b, acc);
  BAR();
  // ---- P3: Mf4-7 x Nf2-3 ----
  if (S) {
    stage2(curB, Bg, 1, T + 2, wave);  // B rows 64-127,192-255
    stage2(curA, Ag, 1, T + 2, wave);  // A rows 64-127,192-255 (read at P2)
  }
  if constexpr (VM == 8) asm volatile("s_waitcnt vmcnt(8)" ::: "memory");
  else if constexpr (VM == 0) asm volatile("s_waitcnt vmcnt(0)" ::: "memory");
  BAR();
  mfma16<4, 2>(a, b, acc);
  BAR();
}

__global__ __launch_bounds__(512, 2) void gemm_bf16_8ph(
    const unsigned short* __restrict__ Ab, const unsigned short* __restrict__ Bt,
    const float* __restrict__ bias, float* __restrict__ out) {
  __shared__ __align__(16) unsigned short lds[4 * BM * BK];  // 128 KiB
  unsigned short* A0 = lds;
  unsigned short* B0 = lds + 1 * BM * BK;
  unsigned short* A1 = lds + 2 * BM * BK;
  unsigned short* B1 = lds + 3 * BM * BK;

  const int tid = threadIdx.x;
  const int lane = tid & 63;
  const int wave = tid >> 6;  // 0..7
  const int wm = wave & 1;    // 2 M-waves (128 rows each)
  const int wn = wave >> 1;   // 4 N-waves (64 cols each)

  // XCD-bijective swizzle: 512 blocks, 64 contiguous output tiles per XCD.
  const int bid = blockIdx.x;
  const int wg = (bid & 7) * 64 + (bid >> 3);
  const int m0 = (wg >> 4) * BM;  // 32 m-tiles
  const int n0 = (wg & 15) * BN;  // 16 n-tiles

  f32x4 acc[8][4];
#pragma unroll
  for (int i = 0; i < 8; ++i)
#pragma unroll
    for (int j = 0; j < 4; ++j) {
      f32x4 z = {0.0f, 0.0f, 0.0f, 0.0f};
      acc[i][j] = z;
    }

  // Staging source: row tr of tile, pre-swizzled chunk (gload_lds linear).
  const int tr = tid >> 3;                    // 0..63
  const int tc = (tid & 7) ^ (tr & 7);
  const unsigned short* Ag = Ab + (size_t)(m0 + tr) * KDIM + tc * 8;
  const unsigned short* Bg = Bt + (size_t)(n0 + tr) * KDIM + tc * 8;

  // ds_read fragment addressing (swizzled chunk read).
  const int rA = lane & 15;
  const int hi = lane >> 4;
  const int key = lane & 7;
  const int k0off = ((0 + hi) ^ key) * 8;
  const int k1off = ((4 + hi) ^ key) * 8;

  bf16x8 a[4][2], b[4][2];

  // Prologue: tile-0 group (8 loads), tile-1 group (8 loads); vmcnt(8)
  // publishes tile 0, keeps tile 1 in flight (matches steady structure).
  stage2(B0, Bg, 0, 0, wave);
  stage2(A0, Ag, 0, 0, wave);
  stage2(B0, Bg, 1, 0, wave);
  stage2(A0, Ag, 1, 0, wave);
  stage2(B1, Bg, 0, 1, wave);
  stage2(A1, Ag, 0, 1, wave);
  stage2(B1, Bg, 1, 1, wave);
  stage2(A1, Ag, 1, 1, wave);
  asm volatile("s_waitcnt vmcnt(8)" ::: "memory");
  BAR();

  // Main loop: tiles 0..61 steady (stage T+2, up to 63), unrolled by 2.
  for (int T = 0; T < NT - 2; T += 2) {
    tile_step<true, 8>(A0, B0, T, Ag, Bg, wave, wm, wn, rA, k0off, k1off, a,
                       b, acc);
    tile_step<true, 8>(A1, B1, T + 1, Ag, Bg, wave, wm, wn, rA, k0off, k1off,
                       a, b, acc);
  }
  // Tile 62: no staging; drain (publishes tile 63, staged at tile 61).
  tile_step<false, 0>(A0, B0, NT - 2, Ag, Bg, wave, wm, wn, rA, k0off, k1off,
                      a, b, acc);
  // Tile 63: pure compute.
  tile_step<false, -1>(A1, B1, NT - 1, Ag, Bg, wave, wm, wn, rA, k0off, k1off,
                       a, b, acc);

  // Epilogue: lane -> m = l&15, n = (l>>4)*4 (+reg), float4 stores.
  float* zout = out + (size_t)MDIM * NDIM;  // output 1 (z) after output 0
  const int ml = lane & 15;
  const int nb4 = (lane >> 4) * 4;
#pragma unroll
  for (int i = 0; i < 8; ++i) {
    int m = m0 + wm * 128 + i * 16 + ml;
    float* zrow = zout + (size_t)m * NDIM;
    float* srow = out + (size_t)m * NDIM;
#pragma unroll
    for (int j = 0; j < 4; ++j) {
      int n = n0 + wn * 64 + j * 16 + nb4;
      float4 bv = *(const float4*)&bias[n];
      f32x4 v = acc[i][j];
      float4 z, s;
      z.x = v[0] + bv.x; z.y = v[1] + bv.y; z.z = v[2] + bv.z; z.w = v[3] + bv.w;
      s.x = (z.x >= 0.0f) ? 1.0f : -1.0f;
      s.y = (z.y >= 0.0f) ? 1.0f : -1.0f;
      s.z = (z.z >= 0.0f) ? 1.0f : -1.0f;
      s.w = (z.w >= 0.0f) ? 1.0f : -1.0f;
      *(float4*)&zrow[n] = z;
      *(float4*)&srow[n] = s;
    }
  }
}

// ---------------- fallback GEMM (128^2, fp32 inputs, no workspace) ----------
__device__ __forceinline__ void mfma_step128(const unsigned short* As,
                                             const unsigned short* Bs,
                                             f32x4 acc[4][4], int lane, int wm,
                                             int wn) {
  const int rA = lane & 15;
  const int key = lane & 7;
#pragma unroll
  for (int kk = 0; kk < 2; ++kk) {
    const int koff = ((kk * 4 + (lane >> 4)) ^ key) * 8;
    bf16x8 a[4], b[4];
#pragma unroll
    for (int i = 0; i < 4; ++i) {
      a[i] = *(const bf16x8*)(As + (size_t)(wm * 64 + i * 16 + rA) * 64 + koff);
      b[i] = *(const bf16x8*)(Bs + (size_t)(wn * 64 + i * 16 + rA) * 64 + koff);
    }
#pragma unroll
    for (int i = 0; i < 4; ++i)
#pragma unroll
      for (int j = 0; j < 4; ++j)
        acc[i][j] = __builtin_amdgcn_mfma_f32_16x16x32_bf16(b[j], a[i],
                                                            acc[i][j], 0, 0, 0);
  }
}

__global__ __launch_bounds__(256) void gemm_bf16_nows(
    const float* __restrict__ x, const float* __restrict__ W,
    const float* __restrict__ bias, float* __restrict__ out) {
  __shared__ __align__(16) unsigned short As[128 * 64];
  __shared__ __align__(16) unsigned short Bs[128 * 64];

  const int tid = threadIdx.x;
  const int lane = tid & 63;
  const int wave = tid >> 6;
  const int wm = wave & 1;
  const int wn = wave >> 1;
  const int m0 = blockIdx.y * 128;
  const int n0 = blockIdx.x * 128;

  f32x4 acc[4][4];
#pragma unroll
  for (int i = 0; i < 4; ++i)
#pragma unroll
    for (int j = 0; j < 4; ++j) {
      f32x4 z = {0.0f, 0.0f, 0.0f, 0.0f};
      acc[i][j] = z;
    }

  for (int k0 = 0; k0 < KDIM; k0 += 64) {
    {
      const int kc = (tid & 15) * 4;
      const int cb = kc >> 3;
      const int wi = kc & 7;
      const int rowb = tid >> 4;
#pragma unroll
      for (int r = 0; r < 8; ++r) {
        int row = rowb + 16 * r;
        float4 v = *(const float4*)&x[(size_t)(m0 + row) * KDIM + k0 + kc];
        uint2 pk;
        pk.x = f2bf(v.x) | (f2bf(v.y) << 16);
        pk.y = f2bf(v.z) | (f2bf(v.w) << 16);
        *(uint2*)&As[row * 64 + ((cb ^ (row & 7)) * 8) + wi] = pk;
      }
    }
    {
      const int nc = (tid & 31) * 4;
      const int kb = tid >> 5;
#pragma unroll
      for (int r = 0; r < 8; ++r) {
        int krow = kb + 8 * r;
        int cb = krow >> 3, wi = krow & 7;
        float4 v = *(const float4*)&W[(size_t)(k0 + krow) * NDIM + n0 + nc];
        Bs[(nc + 0) * 64 + ((cb ^ ((nc + 0) & 7)) * 8) + wi] = (unsigned short)f2bf(v.x);
        Bs[(nc + 1) * 64 + ((cb ^ ((nc + 1) & 7)) * 8) + wi] = (unsigned short)f2bf(v.y);
        Bs[(nc + 2) * 64 + ((cb ^ ((nc + 2) & 7)) * 8) + wi] = (unsigned short)f2bf(v.z);
        Bs[(nc + 3) * 64 + ((cb ^ ((nc + 3) & 7)) * 8) + wi] = (unsigned short)f2bf(v.w);
      }
    }
    __syncthreads();
    mfma_step128(As, Bs, acc, lane, wm, wn);
    __syncthreads();
  }

  float* zout = out + (size_t)MDIM * NDIM;
  const int ml = lane & 15;
  const int nb4 = (lane >> 4) * 4;
#pragma unroll
  for (int i = 0; i < 4; ++i) {
    int m = m0 + wm * 64 + i * 16 + ml;
    float* zrow = zout + (size_t)m * NDIM;
    float* srow = out + (size_t)m * NDIM;
#pragma unroll
    for (int j = 0; j < 4; ++j) {
      int n = n0 + wn * 64 + j * 16 + nb4;
      float4 bv = *(const float4*)&bias[n];
      f32x4 v = acc[i][j];
      float4 z, s;
      z.x = v[0] + bv.x; z.y = v[1] + bv.y; z.z = v[2] + bv.z; z.w = v[3] + bv.w;
      s.x = (z.x >= 0.0f) ? 1.0f : -1.0f;
      s.y = (z.y >= 0.0f) ? 1.0f : -1.0f;
      s.z = (z.z >= 0.0f) ? 1.0f : -1.0f;
      s.w = (z.w >= 0.0f) ? 1.0f : -1.0f;
      *(float4*)&zrow[n] = z;
      *(float4*)&srow[n] = s;
    }
  }
}

// ---------------- launcher ----------------
extern "C" void kernel_launch(void* const* d_in, const int* in_sizes, int n_in,
                              void* d_out, int out_size, void* d_ws,
                              size_t ws_size, hipStream_t stream) {
  (void)in_sizes; (void)n_in; (void)out_size;
  const float* x = (const float*)d_in[0];
  const float* W = (const float*)d_in[1];
  const float* b = (const float*)d_in[2];
  float* out = (float*)d_out;

  const size_t xb_elems = (size_t)MDIM * KDIM;
  const size_t wt_elems = (size_t)KDIM * NDIM;
  const size_t need = (xb_elems + wt_elems) * sizeof(unsigned short);

  if (ws_size >= need) {
    unsigned short* xb = (unsigned short*)d_ws;
    unsigned short* wt = xb + xb_elems;
    cvt_fused<<<CVT_X_BLOCKS + CVT_W_BLOCKS, 256, 0, stream>>>(x, W, xb, wt);
    gemm_bf16_8ph<<<(MDIM / BM) * (NDIM / BN), 512, 0, stream>>>(xb, wt, b, out);
  } else {
    dim3 fgrid(NDIM / 128, MDIM / 128);
    gemm_bf16_nows<<<fgrid, 256, 0, stream>>>(x, W, b, out);
  }
}

// Round 5
// 601.572 us; speedup vs baseline: 1.2936x; 1.0400x over previous
//
#include <hip/hip_runtime.h>
#include <stdint.h>

// Problem dims (fixed): x [M,K] fp32, W [K,N] fp32 ternary, b [N] fp32.
// out = concat( sign(z) [M,N], z [M,N] ), z = x@W + b, all fp32.
#define MDIM 8192
#define NDIM 4096
#define KDIM 4096

// 8-phase GEMM geometry (256x256 tile, BK=64, 8 waves 2Mx4N)
#define BM 256
#define BN 256
#define BK 64
#define NT (KDIM / BK)  // 64 K-tiles

#define CVT_X_BLOCKS 16384  // M*K/(256*8)
#define CVT_W_BLOCKS 4096   // (N/64)*(K/64)

typedef __bf16 bf16x8 __attribute__((ext_vector_type(8)));
typedef float f32x4 __attribute__((ext_vector_type(4)));

#define GPTR(p) ((const __attribute__((address_space(1))) void*)(p))
#define LPTR(p) ((__attribute__((address_space(3))) void*)(p))

// Raw barrier with compiler memory fence.
#define BAR() asm volatile("s_barrier" ::: "memory")

__device__ __forceinline__ uint32_t f2bf(float f) {
  union { float f; uint32_t u; } c; c.f = f;
  uint32_t u = c.u;
  u += 0x7fffu + ((u >> 16) & 1u);   // RTNE (NaN irrelevant for this data)
  return u >> 16;
}

// ---------------- fused conversion kernel (round-1 verified) ----------------
__global__ __launch_bounds__(256) void cvt_fused(const float* __restrict__ x,
                                                 const float* __restrict__ W,
                                                 unsigned short* __restrict__ xb,
                                                 unsigned short* __restrict__ Wt) {
  __shared__ uint32_t T[64][37];
  const int bid = blockIdx.x;
  const int t = threadIdx.x;
  if (bid < CVT_X_BLOCKS) {
    size_t i = ((size_t)bid * 256 + t) * 8;
    const float4* p = (const float4*)(x + i);
    float4 a = p[0], b = p[1];
    uint4 r;
    r.x = f2bf(a.x) | (f2bf(a.y) << 16);
    r.y = f2bf(a.z) | (f2bf(a.w) << 16);
    r.z = f2bf(b.x) | (f2bf(b.y) << 16);
    r.w = f2bf(b.z) | (f2bf(b.w) << 16);
    *(uint4*)(xb + i) = r;
  } else {
    const int wb = bid - CVT_X_BLOCKS;
    const int n0 = (wb & 63) * 64;
    const int k0 = (wb >> 6) * 64;
    const int nl = t & 63;
    const int kpb = t >> 6;  // 0..3
#pragma unroll
    for (int i = 0; i < 8; ++i) {
      int kp = kpb + 4 * i;  // pair of k rows
      int k = 2 * kp;
      float v0 = W[(size_t)(k0 + k) * NDIM + n0 + nl];
      float v1 = W[(size_t)(k0 + k + 1) * NDIM + n0 + nl];
      T[nl][kp] = f2bf(v0) | (f2bf(v1) << 16);
    }
    __syncthreads();
    const int ch = t & 7;   // 16B chunk (8 k)
    const int nb = t >> 3;  // 0..31
#pragma unroll
    for (int h = 0; h < 2; ++h) {
      int n = nb + 32 * h;
      uint4 v;
      v.x = T[n][ch * 4 + 0];
      v.y = T[n][ch * 4 + 1];
      v.z = T[n][ch * 4 + 2];
      v.w = T[n][ch * 4 + 3];
      *(uint4*)&Wt[(size_t)(n0 + n) * KDIM + k0 + ch * 8] = v;
    }
  }
}

// ---------------- 8-phase 256x256 GEMM (round-1 schedule, kk-split phases) --
// LDS layout per operand tile: [256 rows][64 K] bf16; chunk c of row r stored
// at chunk position c ^ (r&7) (zero-conflict ds_read_b128, verified).
// Staging: global_load_lds with pre-swizzled global source (rule 21).
//
// ROUND-1 STAGING (proven 251us/46%): 2 stage-issues EVERY phase, spread:
//   P0: A(T+1) half0 -> nxtA      P1: A(T+1) half1 -> nxtA
//   P2: B(T+2) half0 -> curB      P3: B(T+2) half1 -> curB, then vmcnt(4)
// vmcnt(4) at P3 completes A(T+1)+B(T+1) (publishes tile T+1), keeps the
// B(T+2) 4 loads in flight. Round-4's burst variant (all 8 in P2/P3,
// vmcnt(8)) REGRESSED to 293us: issue burst + same-phase LDS write/read
// contention. Spread interleave is the lever, not pipeline depth.
//
// PHASE REBALANCE (new vs round-1): MFMA quadrants split by (M-half x kk)
// instead of (M-half x N-half): each phase = 16 INDEPENDENT MFMAs (no acc
// chains), ds_reads balance to 8/8/8/0 (round-1 was 12/4/8/0).
//   P0: read a(0-3,k0), b(:,k0) -> mfma a03k0 x b k0
//   P1: read a(0-3,k1), b(:,k1) -> mfma a03k1 x b k1
//   P2: read a(4-7,k0), a(4-7,k1) -> mfma a47k0 x b k0
//   P3: (no reads)               -> mfma a47k1 x b k1
// Liveness: curB rows all last READ at P1 -> staged P2/P3 (barrier-separated,
// safe). nxtA last read at tile T-1 P2 -> staged from tile T P0 (2 barriers).

__device__ __forceinline__ void stage2(unsigned short* dst,
                                       const unsigned short* G, int half,
                                       int tile, int wave) {
#pragma unroll
  for (int i = 0; i < 2; ++i) {
    const int rb = half * 128 + i * 64;  // 64 rows per instruction (512 thr)
    __builtin_amdgcn_global_load_lds(
        GPTR(G + (size_t)rb * KDIM + (size_t)tile * 64),
        LPTR(dst + (rb + wave * 8) * BK), 16, 0, 0);
  }
}

// 4 A-fragment reads (one kk chunk) for M-frags IB..IB+3.
template <int IB>
__device__ __forceinline__ void load_a4k(const unsigned short* buf, int wm,
                                         int rA, int koff, bf16x8 (&a)[4]) {
#pragma unroll
  for (int i = 0; i < 4; ++i)
    a[i] = *(const bf16x8*)(buf + (size_t)(wm * 128 + (IB + i) * 16 + rA) * BK +
                            koff);
}

// 4 B-fragment reads (one kk chunk), all N-frags.
__device__ __forceinline__ void load_b4k(const unsigned short* buf, int wn,
                                         int rA, int koff, bf16x8 (&b)[4]) {
#pragma unroll
  for (int j = 0; j < 4; ++j)
    b[j] = *(const bf16x8*)(buf + (size_t)(wn * 64 + j * 16 + rA) * BK + koff);
}

// OPERAND SWAP (verified): acc = mfma(b, a, acc) -> lane l: m = l&15,
// n = (l>>4)*4 + reg  => float4 epilogue stores along n.
// 16 MFMAs on 16 DISTINCT accumulators (no chains).
template <int IB>
__device__ __forceinline__ void mfma16q(const bf16x8 (&a)[4],
                                        const bf16x8 (&b)[4],
                                        f32x4 (&acc)[8][4]) {
  __builtin_amdgcn_s_setprio(1);
#pragma unroll
  for (int i = 0; i < 4; ++i)
#pragma unroll
    for (int j = 0; j < 4; ++j)
      acc[IB + i][j] = __builtin_amdgcn_mfma_f32_16x16x32_bf16(
          b[j], a[i], acc[IB + i][j], 0, 0, 0);
  __builtin_amdgcn_s_setprio(0);
}

// SA: stage A(T+1) into nxtA. SB: stage B(T+2) into curB.
// VM: 4 = steady counted wait, 0 = drain (tile 62), -1 = none (tile 63).
template <bool SA, bool SB, int VM>
__device__ __forceinline__ void tile_step(
    const unsigned short* curA, unsigned short* curB, unsigned short* nxtA,
    int T, const unsigned short* Ag, const unsigned short* Bg, int wave,
    int wm, int wn, int rA, int k0off, int k1off, f32x4 (&acc)[8][4]) {
  bf16x8 aL[4], aH[4], b0[4], b1[4];
  // ---- P0: Mf0-3 x all-N x kk0 ----
  load_a4k<0>(curA, wm, rA, k0off, aL);
  load_b4k(curB, wn, rA, k0off, b0);
  if (SA) stage2(nxtA, Ag, 0, T + 1, wave);
  BAR();
  mfma16q<0>(aL, b0, acc);
  BAR();
  // ---- P1: Mf0-3 x all-N x kk1 ----
  load_a4k<0>(curA, wm, rA, k1off, aH);
  load_b4k(curB, wn, rA, k1off, b1);
  if (SA) stage2(nxtA, Ag, 1, T + 1, wave);
  BAR();
  mfma16q<0>(aH, b1, acc);
  BAR();
  // ---- P2: Mf4-7 x all-N x kk0 ----
  load_a4k<4>(curA, wm, rA, k0off, aL);
  load_a4k<4>(curA, wm, rA, k1off, aH);
  if (SB) stage2(curB, Bg, 0, T + 2, wave);
  BAR();
  mfma16q<4>(aL, b0, acc);
  BAR();
  // ---- P3: Mf4-7 x all-N x kk1 ----
  if (SB) stage2(curB, Bg, 1, T + 2, wave);
  if constexpr (VM == 4) asm volatile("s_waitcnt vmcnt(4)" ::: "memory");
  else if constexpr (VM == 0) asm volatile("s_waitcnt vmcnt(0)" ::: "memory");
  BAR();
  mfma16q<4>(aH, b1, acc);
  BAR();
}

__global__ __launch_bounds__(512, 2) void gemm_bf16_8ph(
    const unsigned short* __restrict__ Ab, const unsigned short* __restrict__ Bt,
    const float* __restrict__ bias, float* __restrict__ out) {
  __shared__ __align__(16) unsigned short lds[4 * BM * BK];  // 128 KiB
  unsigned short* A0 = lds;
  unsigned short* B0 = lds + 1 * BM * BK;
  unsigned short* A1 = lds + 2 * BM * BK;
  unsigned short* B1 = lds + 3 * BM * BK;

  const int tid = threadIdx.x;
  const int lane = tid & 63;
  const int wave = tid >> 6;  // 0..7
  const int wm = wave & 1;    // 2 M-waves (128 rows each)
  const int wn = wave >> 1;   // 4 N-waves (64 cols each)

  // XCD-bijective swizzle: 512 blocks, 64 contiguous output tiles per XCD.
  const int bid = blockIdx.x;
  const int wg = (bid & 7) * 64 + (bid >> 3);
  const int m0 = (wg >> 4) * BM;  // 32 m-tiles
  const int n0 = (wg & 15) * BN;  // 16 n-tiles

  f32x4 acc[8][4];
#pragma unroll
  for (int i = 0; i < 8; ++i)
#pragma unroll
    for (int j = 0; j < 4; ++j) {
      f32x4 z = {0.0f, 0.0f, 0.0f, 0.0f};
      acc[i][j] = z;
    }

  // Staging source: row tr of tile, pre-swizzled chunk (gload_lds linear).
  const int tr = tid >> 3;                    // 0..63
  const int tc = (tid & 7) ^ (tr & 7);
  const unsigned short* Ag = Ab + (size_t)(m0 + tr) * KDIM + tc * 8;
  const unsigned short* Bg = Bt + (size_t)(n0 + tr) * KDIM + tc * 8;

  // ds_read fragment addressing (swizzled chunk read).
  const int rA = lane & 15;
  const int hi = lane >> 4;
  const int key = lane & 7;
  const int k0off = ((0 + hi) ^ key) * 8;
  const int k1off = ((4 + hi) ^ key) * 8;

  // Prologue (round-1): B0, A0, B1 staged; vmcnt(4) publishes tile 0,
  // keeps B1's 4 loads in flight (tile 0's P0/P1 then stages A1).
  stage2(B0, Bg, 0, 0, wave);
  stage2(B0, Bg, 1, 0, wave);
  stage2(A0, Ag, 0, 0, wave);
  stage2(A0, Ag, 1, 0, wave);
  stage2(B1, Bg, 0, 1, wave);
  stage2(B1, Bg, 1, 1, wave);
  asm volatile("s_waitcnt vmcnt(4)" ::: "memory");
  BAR();

  // Main loop: tiles 0..61 steady-state, unrolled by 2 for static buffers.
  for (int T = 0; T < NT - 2; T += 2) {
    tile_step<true, true, 4>(A0, B0, A1, T, Ag, Bg, wave, wm, wn, rA, k0off,
                             k1off, acc);
    tile_step<true, true, 4>(A1, B1, A0, T + 1, Ag, Bg, wave, wm, wn, rA,
                             k0off, k1off, acc);
  }
  // Tile 62: stage A(63) only; drain (publishes A(63); B(63) staged @ 61).
  tile_step<true, false, 0>(A0, B0, A1, NT - 2, Ag, Bg, wave, wm, wn, rA,
                            k0off, k1off, acc);
  // Tile 63: pure compute.
  tile_step<false, false, -1>(A1, B1, A0, NT - 1, Ag, Bg, wave, wm, wn, rA,
                              k0off, k1off, acc);

  // Epilogue: lane -> m = l&15, n = (l>>4)*4 (+reg), float4 stores.
  float* zout = out + (size_t)MDIM * NDIM;  // output 1 (z) after output 0
  const int ml = lane & 15;
  const int nb4 = (lane >> 4) * 4;
#pragma unroll
  for (int i = 0; i < 8; ++i) {
    int m = m0 + wm * 128 + i * 16 + ml;
    float* zrow = zout + (size_t)m * NDIM;
    float* srow = out + (size_t)m * NDIM;
#pragma unroll
    for (int j = 0; j < 4; ++j) {
      int n = n0 + wn * 64 + j * 16 + nb4;
      float4 bv = *(const float4*)&bias[n];
      f32x4 v = acc[i][j];
      float4 z, s;
      z.x = v[0] + bv.x; z.y = v[1] + bv.y; z.z = v[2] + bv.z; z.w = v[3] + bv.w;
      s.x = (z.x >= 0.0f) ? 1.0f : -1.0f;
      s.y = (z.y >= 0.0f) ? 1.0f : -1.0f;
      s.z = (z.z >= 0.0f) ? 1.0f : -1.0f;
      s.w = (z.w >= 0.0f) ? 1.0f : -1.0f;
      *(float4*)&zrow[n] = z;
      *(float4*)&srow[n] = s;
    }
  }
}

// ---------------- fallback GEMM (128^2, fp32 inputs, no workspace) ----------
__device__ __forceinline__ void mfma_step128(const unsigned short* As,
                                             const unsigned short* Bs,
                                             f32x4 acc[4][4], int lane, int wm,
                                             int wn) {
  const int rA = lane & 15;
  const int key = lane & 7;
#pragma unroll
  for (int kk = 0; kk < 2; ++kk) {
    const int koff = ((kk * 4 + (lane >> 4)) ^ key) * 8;
    bf16x8 a[4], b[4];
#pragma unroll
    for (int i = 0; i < 4; ++i) {
      a[i] = *(const bf16x8*)(As + (size_t)(wm * 64 + i * 16 + rA) * 64 + koff);
      b[i] = *(const bf16x8*)(Bs + (size_t)(wn * 64 + i * 16 + rA) * 64 + koff);
    }
#pragma unroll
    for (int i = 0; i < 4; ++i)
#pragma unroll
      for (int j = 0; j < 4; ++j)
        acc[i][j] = __builtin_amdgcn_mfma_f32_16x16x32_bf16(b[j], a[i],
                                                            acc[i][j], 0, 0, 0);
  }
}

__global__ __launch_bounds__(256) void gemm_bf16_nows(
    const float* __restrict__ x, const float* __restrict__ W,
    const float* __restrict__ bias, float* __restrict__ out) {
  __shared__ __align__(16) unsigned short As[128 * 64];
  __shared__ __align__(16) unsigned short Bs[128 * 64];

  const int tid = threadIdx.x;
  const int lane = tid & 63;
  const int wave = tid >> 6;
  const int wm = wave & 1;
  const int wn = wave >> 1;
  const int m0 = blockIdx.y * 128;
  const int n0 = blockIdx.x * 128;

  f32x4 acc[4][4];
#pragma unroll
  for (int i = 0; i < 4; ++i)
#pragma unroll
    for (int j = 0; j < 4; ++j) {
      f32x4 z = {0.0f, 0.0f, 0.0f, 0.0f};
      acc[i][j] = z;
    }

  for (int k0 = 0; k0 < KDIM; k0 += 64) {
    {
      const int kc = (tid & 15) * 4;
      const int cb = kc >> 3;
      const int wi = kc & 7;
      const int rowb = tid >> 4;
#pragma unroll
      for (int r = 0; r < 8; ++r) {
        int row = rowb + 16 * r;
        float4 v = *(const float4*)&x[(size_t)(m0 + row) * KDIM + k0 + kc];
        uint2 pk;
        pk.x = f2bf(v.x) | (f2bf(v.y) << 16);
        pk.y = f2bf(v.z) | (f2bf(v.w) << 16);
        *(uint2*)&As[row * 64 + ((cb ^ (row & 7)) * 8) + wi] = pk;
      }
    }
    {
      const int nc = (tid & 31) * 4;
      const int kb = tid >> 5;
#pragma unroll
      for (int r = 0; r < 8; ++r) {
        int krow = kb + 8 * r;
        int cb = krow >> 3, wi = krow & 7;
        float4 v = *(const float4*)&W[(size_t)(k0 + krow) * NDIM + n0 + nc];
        Bs[(nc + 0) * 64 + ((cb ^ ((nc + 0) & 7)) * 8) + wi] = (unsigned short)f2bf(v.x);
        Bs[(nc + 1) * 64 + ((cb ^ ((nc + 1) & 7)) * 8) + wi] = (unsigned short)f2bf(v.y);
        Bs[(nc + 2) * 64 + ((cb ^ ((nc + 2) & 7)) * 8) + wi] = (unsigned short)f2bf(v.z);
        Bs[(nc + 3) * 64 + ((cb ^ ((nc + 3) & 7)) * 8) + wi] = (unsigned short)f2bf(v.w);
      }
    }
    __syncthreads();
    mfma_step128(As, Bs, acc, lane, wm, wn);
    __syncthreads();
  }

  float* zout = out + (size_t)MDIM * NDIM;
  const int ml = lane & 15;
  const int nb4 = (lane >> 4) * 4;
#pragma unroll
  for (int i = 0; i < 4; ++i) {
    int m = m0 + wm * 64 + i * 16 + ml;
    float* zrow = zout + (size_t)m * NDIM;
    float* srow = out + (size_t)m * NDIM;
#pragma unroll
    for (int j = 0; j < 4; ++j) {
      int n = n0 + wn * 64 + j * 16 + nb4;
      float4 bv = *(const float4*)&bias[n];
      f32x4 v = acc[i][j];
      float4 z, s;
      z.x = v[0] + bv.x; z.y = v[1] + bv.y; z.z = v[2] + bv.z; z.w = v[3] + bv.w;
      s.x = (z.x >= 0.0f) ? 1.0f : -1.0f;
      s.y = (z.y >= 0.0f) ? 1.0f : -1.0f;
      s.z = (z.z >= 0.0f) ? 1.0f : -1.0f;
      s.w = (z.w >= 0.0f) ? 1.0f : -1.0f;
      *(float4*)&zrow[n] = z;
      *(float4*)&srow[n] = s;
    }
  }
}

// ---------------- launcher ----------------
extern "C" void kernel_launch(void* const* d_in, const int* in_sizes, int n_in,
                              void* d_out, int out_size, void* d_ws,
                              size_t ws_size, hipStream_t stream) {
  (void)in_sizes; (void)n_in; (void)out_size;
  const float* x = (const float*)d_in[0];
  const float* W = (const float*)d_in[1];
  const float* b = (const float*)d_in[2];
  float* out = (float*)d_out;

  const size_t xb_elems = (size_t)MDIM * KDIM;
  const size_t wt_elems = (size_t)KDIM * NDIM;
  const size_t need = (xb_elems + wt_elems) * sizeof(unsigned short);

  if (ws_size >= need) {
    unsigned short* xb = (unsigned short*)d_ws;
    unsigned short* wt = xb + xb_elems;
    cvt_fused<<<CVT_X_BLOCKS + CVT_W_BLOCKS, 256, 0, stream>>>(x, W, xb, wt);
    gemm_bf16_8ph<<<(MDIM / BM) * (NDIM / BN), 512, 0, stream>>>(xb, wt, b, out);
  } else {
    dim3 fgrid(NDIM / 128, MDIM / 128);
    gemm_bf16_nows<<<fgrid, 256, 0, stream>>>(x, W, b, out);
  }
}